// Round 1
// baseline (1323.477 us; speedup 1.0000x reference)
//
#include <hip/hip_runtime.h>

using u32 = unsigned int;
using s64 = long long;

// -------- int width detection (int64 iff hi-words of first 64 entries all 0) --------
__global__ __launch_bounds__(64) void k_detect13(const u32* __restrict__ ei,
                                                 const u32* __restrict__ nt,
                                                 const u32* __restrict__ tp,
                                                 u32* __restrict__ flags) {
    if (blockIdx.x != 0 || threadIdx.x != 0) return;
    bool e64 = true, n64 = true, t64 = true;
    for (int k = 0; k < 64; ++k) {
        if (ei[2 * k + 1] != 0u) e64 = false;
        if (nt[2 * k + 1] != 0u) n64 = false;
        if (tp[2 * k + 1] != 0u) t64 = false;
    }
    flags[0] = e64 ? 1u : 0u;
    flags[1] = n64 ? 1u : 0u;
    flags[2] = t64 ? 1u : 0u;
}

// -------- width-adaptive convert to int32 --------
__global__ __launch_bounds__(256) void k_cvt13(const void* __restrict__ src,
                                               int* __restrict__ dst, long long n,
                                               const u32* __restrict__ flags, int fidx) {
    long long i = (long long)blockIdx.x * 256 + threadIdx.x;
    if (i >= n) return;
    dst[i] = flags[fidx] ? (int)((const s64*)src)[i] : ((const int*)src)[i];
}

// ---------------- zero ----------------
__global__ __launch_bounds__(256) void kz13(float* __restrict__ p, long long n) {
    long long i = (long long)blockIdx.x * 256 + threadIdx.x;
    if (i < n) p[i] = 0.f;
}

// wave-wide sum over 64 lanes
__device__ __forceinline__ float wredsum(float v) {
#pragma unroll
    for (int o = 32; o; o >>= 1) v += __shfl_xor(v, o);
    return v;
}

// ---------------- QKV: 4 nodes per wave, shfl-broadcast x ----------------
__global__ __launch_bounds__(256) void k_qkvB(const float* __restrict__ x,
                                              const float* __restrict__ Wq,
                                              const float* __restrict__ Wk,
                                              const float* __restrict__ Wv,
                                              float* __restrict__ big, int N) {
    int l = threadIdx.x & 63;
    int i0 = (blockIdx.x * 4 + (threadIdx.x >> 6)) * 4;
    if (i0 >= N) return;
    int nn = N - i0; if (nn > 4) nn = 4;
    float zr[4][2];
#pragma unroll
    for (int n = 0; n < 4; ++n) {
        int i = i0 + (n < nn ? n : 0);
        zr[n][0] = x[(size_t)i * 128 + l];
        zr[n][1] = x[(size_t)i * 128 + 64 + l];
    }
    float aq[4][2], ak[4][2], av[4][2];
#pragma unroll
    for (int n = 0; n < 4; ++n) {
        aq[n][0] = aq[n][1] = ak[n][0] = ak[n][1] = av[n][0] = av[n][1] = 0.f;
    }
#pragma unroll
    for (int c = 0; c < 2; ++c) {
#pragma unroll 8
        for (int k2 = 0; k2 < 64; ++k2) {
            int k = c * 64 + k2;
            float wq0 = Wq[k * 128 + l], wq1 = Wq[k * 128 + 64 + l];
            float wk0 = Wk[k * 128 + l], wk1 = Wk[k * 128 + 64 + l];
            float wv0 = Wv[k * 128 + l], wv1 = Wv[k * 128 + 64 + l];
#pragma unroll
            for (int n = 0; n < 4; ++n) {
                float xk = __shfl(zr[n][c], k2);
                aq[n][0] = fmaf(xk, wq0, aq[n][0]); aq[n][1] = fmaf(xk, wq1, aq[n][1]);
                ak[n][0] = fmaf(xk, wk0, ak[n][0]); ak[n][1] = fmaf(xk, wk1, ak[n][1]);
                av[n][0] = fmaf(xk, wv0, av[n][0]); av[n][1] = fmaf(xk, wv1, av[n][1]);
            }
        }
    }
#pragma unroll
    for (int n = 0; n < 4; ++n) if (n < nn) {
        size_t b = (size_t)(i0 + n) * 384;
        big[b + l] = aq[n][0];        big[b + 64 + l] = aq[n][1];
        big[b + 128 + l] = ak[n][0];  big[b + 192 + l] = ak[n][1];
        big[b + 256 + l] = av[n][0];  big[b + 320 + l] = av[n][1];
    }
}

// ---------------- GAT scores (float4 gathers): exp + segment denominator ----------------
__global__ __launch_bounds__(256) void k_gat_smB(const float* __restrict__ big,
                                                 const int* __restrict__ ei, int E,
                                                 float* __restrict__ scores,
                                                 float* __restrict__ sm) {
    long long t = (long long)blockIdx.x * 256 + threadIdx.x;
    if (t >= (long long)E * 8) return;
    int e = (int)(t >> 3), h = (int)(t & 7);
    int row = ei[e], col = ei[E + e];
    const float4* q = (const float4*)(big + (size_t)row * 384 + h * 16);
    const float4* kk = (const float4*)(big + (size_t)col * 384 + 128 + h * 16);
    float s = 0.f;
#pragma unroll
    for (int d = 0; d < 4; ++d) {
        float4 a = q[d], b = kk[d];
        s += a.x * b.x + a.y * b.y + a.z * b.z + a.w * b.w;
    }
    s *= 0.25f;
    s = s > 0.f ? s : 0.2f * s;
    float ex = expf(s);
    scores[t] = ex;
    atomicAdd(&sm[(size_t)col * 8 + h], ex);
}

// ---------------- GAT weighted-V scatter ----------------
__global__ __launch_bounds__(256) void k_gat_wv13(const float* __restrict__ big,
                                                  const int* __restrict__ ei, int E,
                                                  const float* __restrict__ scores,
                                                  const float* __restrict__ sm,
                                                  float* __restrict__ agg) {
    long long t = (long long)blockIdx.x * 256 + threadIdx.x;
    if (t >= (long long)E * 128) return;
    int e = (int)(t >> 7), j = (int)(t & 127);
    int row = ei[e], col = ei[E + e];
    int h = j >> 4;
    float p = scores[(size_t)e * 8 + h] / sm[(size_t)col * 8 + h];
    atomicAdd(&agg[(size_t)col * 128 + j], p * big[(size_t)row * 384 + 256 + j]);
}

// ---------------- GAT epilogue: obr = LN(agg@Wo + bo + x), 4 nodes/wave ----------------
__global__ __launch_bounds__(256) void k_ep_gatB(const float* __restrict__ x,
                                                 const float* __restrict__ agg,
                                                 const float* __restrict__ Wo,
                                                 const float* __restrict__ bo,
                                                 const float* __restrict__ g,
                                                 const float* __restrict__ b,
                                                 float* __restrict__ obr, int N) {
    int l = threadIdx.x & 63;
    int i0 = (blockIdx.x * 4 + (threadIdx.x >> 6)) * 4;
    if (i0 >= N) return;
    int nn = N - i0; if (nn > 4) nn = 4;
    float zr[4][2];
#pragma unroll
    for (int n = 0; n < 4; ++n) {
        int i = i0 + (n < nn ? n : 0);
        zr[n][0] = agg[(size_t)i * 128 + l];
        zr[n][1] = agg[(size_t)i * 128 + 64 + l];
    }
    float b0 = bo[l], b1v = bo[64 + l];
    float ac[4][2];
#pragma unroll
    for (int n = 0; n < 4; ++n) { ac[n][0] = b0; ac[n][1] = b1v; }
#pragma unroll
    for (int c = 0; c < 2; ++c) {
#pragma unroll 8
        for (int k2 = 0; k2 < 64; ++k2) {
            int k = c * 64 + k2;
            float w0 = Wo[k * 128 + l], w1 = Wo[k * 128 + 64 + l];
#pragma unroll
            for (int n = 0; n < 4; ++n) {
                float xk = __shfl(zr[n][c], k2);
                ac[n][0] = fmaf(xk, w0, ac[n][0]);
                ac[n][1] = fmaf(xk, w1, ac[n][1]);
            }
        }
    }
    float g0 = g[l], g1 = g[64 + l], bb0 = b[l], bb1 = b[64 + l];
#pragma unroll
    for (int n = 0; n < 4; ++n) if (n < nn) {
        int i = i0 + n;
        float v0 = ac[n][0] + x[(size_t)i * 128 + l];
        float v1 = ac[n][1] + x[(size_t)i * 128 + 64 + l];
        float m = wredsum(v0 + v1) * 0.0078125f;
        float d0 = v0 - m, d1 = v1 - m;
        float r = rsqrtf(wredsum(d0 * d0 + d1 * d1) * 0.0078125f + 1e-5f);
        obr[(size_t)i * 128 + l]      = d0 * r * g0 + bb0;
        obr[(size_t)i * 128 + 64 + l] = d1 * r * g1 + bb1;
    }
}

// ---------------- per-type transform: h_gcn = x@Wt[t] + bt[t] ----------------
__global__ __launch_bounds__(64) void k_hgcn13(const float* __restrict__ x,
                                               const int* __restrict__ nt,
                                               const float* __restrict__ Wt,
                                               const float* __restrict__ bt,
                                               float* __restrict__ h_gcn) {
    int i = blockIdx.x, j = threadIdx.x;
    int t = nt[i];
    t = (t < 0 || t > 5) ? 0 : t;
    const float* W = Wt + (size_t)t * 16384;
    float a0 = bt[t * 128 + j], a1 = bt[t * 128 + 64 + j];
    for (int k = 0; k < 128; ++k) {
        float xa = x[(size_t)i * 128 + k];
        a0 += xa * W[k * 128 + j];
        a1 += xa * W[k * 128 + 64 + j];
    }
    h_gcn[(size_t)i * 128 + j] = a0;
    h_gcn[(size_t)i * 128 + 64 + j] = a1;
}

// ---------------- h_tmp = x + emb[clip(tpos)] ----------------
__global__ __launch_bounds__(256) void k_htmp13(const float* __restrict__ x,
                                                const float* __restrict__ emb,
                                                const int* __restrict__ tpos,
                                                float* __restrict__ h_tmp, int N) {
    long long t = (long long)blockIdx.x * 256 + threadIdx.x;
    if (t >= (long long)N * 128) return;
    int i = (int)(t >> 7), j = (int)(t & 127);
    int tp = tpos[i]; tp = tp < 0 ? 0 : (tp > 49 ? 49 : tp);
    h_tmp[t] = x[t] + emb[tp * 128 + j];
}

// ------- layer-1 precompute: Pa = h@W1[0:128], Pb = h@W1[128:256] + b1 -------
__global__ __launch_bounds__(256) void k_preB(const float* __restrict__ h,
                                              const float* __restrict__ W1,
                                              const float* __restrict__ b1,
                                              float* __restrict__ Pa,
                                              float* __restrict__ Pb, int N) {
    int l = threadIdx.x & 63;
    int i0 = (blockIdx.x * 4 + (threadIdx.x >> 6)) * 4;
    if (i0 >= N) return;
    int nn = N - i0; if (nn > 4) nn = 4;
    float zr[4][2];
#pragma unroll
    for (int n = 0; n < 4; ++n) {
        int i = i0 + (n < nn ? n : 0);
        zr[n][0] = h[(size_t)i * 128 + l];
        zr[n][1] = h[(size_t)i * 128 + 64 + l];
    }
    float bb0 = b1[l], bb1 = b1[64 + l];
    float aa[4][2], ab[4][2];
#pragma unroll
    for (int n = 0; n < 4; ++n) { aa[n][0] = aa[n][1] = 0.f; ab[n][0] = bb0; ab[n][1] = bb1; }
#pragma unroll
    for (int c = 0; c < 2; ++c) {
#pragma unroll 8
        for (int k2 = 0; k2 < 64; ++k2) {
            int k = c * 64 + k2;
            float wa0 = W1[k * 128 + l],           wa1 = W1[k * 128 + 64 + l];
            float wb0 = W1[(k + 128) * 128 + l],   wb1 = W1[(k + 128) * 128 + 64 + l];
#pragma unroll
            for (int n = 0; n < 4; ++n) {
                float xk = __shfl(zr[n][c], k2);
                aa[n][0] = fmaf(xk, wa0, aa[n][0]); aa[n][1] = fmaf(xk, wa1, aa[n][1]);
                ab[n][0] = fmaf(xk, wb0, ab[n][0]); ab[n][1] = fmaf(xk, wb1, ab[n][1]);
            }
        }
    }
#pragma unroll
    for (int n = 0; n < 4; ++n) if (n < nn) {
        size_t o = (size_t)(i0 + n) * 128;
        Pa[o + l] = aa[n][0]; Pa[o + 64 + l] = aa[n][1];
        Pb[o + l] = ab[n][0]; Pb[o + 64 + l] = ab[n][1];
    }
}

// ------- edge MLP layer 2 only: agg[col] += relu(Pa[row]+Pb[col]) @ W2 + b2 -------
__global__ __launch_bounds__(512) void k_mlp2(const float* __restrict__ Pa,
                                              const float* __restrict__ Pb,
                                              const int* __restrict__ ei, int E,
                                              const float* __restrict__ W2,
                                              const float* __restrict__ b2,
                                              float* __restrict__ agg) {
    __shared__ float w2s[16384];  // 64 KB: all of W2
    for (int i = threadIdx.x; i < 16384; i += 512) w2s[i] = W2[i];
    __syncthreads();
    int l = threadIdx.x & 63;
    int wid = blockIdx.x * 8 + (threadIdx.x >> 6);
    int nw = gridDim.x * 8;
    float b20 = b2[l], b21 = b2[64 + l];
    for (int e0 = wid * 4; e0 < E; e0 += nw * 4) {
        int ne = E - e0; if (ne > 4) ne = 4;
        int colv[4];
        float z[4][2];
#pragma unroll
        for (int n = 0; n < 4; ++n) {
            int e = e0 + (n < ne ? n : 0);
            int row = ei[e], col = ei[E + e];
            colv[n] = col;
            float z0 = Pa[(size_t)row * 128 + l]      + Pb[(size_t)col * 128 + l];
            float z1 = Pa[(size_t)row * 128 + 64 + l] + Pb[(size_t)col * 128 + 64 + l];
            z[n][0] = z0 > 0.f ? z0 : 0.f;
            z[n][1] = z1 > 0.f ? z1 : 0.f;
        }
        float ac[4][2];
#pragma unroll
        for (int n = 0; n < 4; ++n) { ac[n][0] = b20; ac[n][1] = b21; }
#pragma unroll
        for (int c = 0; c < 2; ++c) {
#pragma unroll 8
            for (int k2 = 0; k2 < 64; ++k2) {
                int k = c * 64 + k2;
                float w0 = w2s[k * 128 + l], w1 = w2s[k * 128 + 64 + l];
#pragma unroll
                for (int n = 0; n < 4; ++n) {
                    float xk = __shfl(z[n][c], k2);
                    ac[n][0] = fmaf(xk, w0, ac[n][0]);
                    ac[n][1] = fmaf(xk, w1, ac[n][1]);
                }
            }
        }
#pragma unroll
        for (int n = 0; n < 4; ++n) if (n < ne) {
            atomicAdd(&agg[(size_t)colv[n] * 128 + l],      ac[n][0]);
            atomicAdd(&agg[(size_t)colv[n] * 128 + 64 + l], ac[n][1]);
        }
    }
}

// ---------------- GCN epilogue, 4 nodes/wave, 3 chained matmuls ----------------
__global__ __launch_bounds__(256) void k_ep_gcnB(const float* __restrict__ x,
                                                 const float* __restrict__ h_gcn,
                                                 const float* __restrict__ agg,
                                                 const float* __restrict__ aW1,
                                                 const float* __restrict__ ab1,
                                                 const float* __restrict__ aW2,
                                                 const float* __restrict__ ab2,
                                                 const float* __restrict__ Wo,
                                                 const float* __restrict__ bo,
                                                 const float* __restrict__ g,
                                                 const float* __restrict__ b,
                                                 float* __restrict__ obr, int N) {
    int l = threadIdx.x & 63;
    int i0 = (blockIdx.x * 4 + (threadIdx.x >> 6)) * 4;
    if (i0 >= N) return;
    int nn = N - i0; if (nn > 4) nn = 4;
    float zr[4][2];
#pragma unroll
    for (int n = 0; n < 4; ++n) {
        int i = i0 + (n < nn ? n : 0);
        zr[n][0] = agg[(size_t)i * 128 + l];
        zr[n][1] = agg[(size_t)i * 128 + 64 + l];
    }
    // matmul 1: u = relu(agg@aW1 + ab1)
    float c10 = ab1[l], c11 = ab1[64 + l];
    float u[4][2];
#pragma unroll
    for (int n = 0; n < 4; ++n) { u[n][0] = c10; u[n][1] = c11; }
#pragma unroll
    for (int c = 0; c < 2; ++c) {
#pragma unroll 8
        for (int k2 = 0; k2 < 64; ++k2) {
            int k = c * 64 + k2;
            float w0 = aW1[k * 128 + l], w1 = aW1[k * 128 + 64 + l];
#pragma unroll
            for (int n = 0; n < 4; ++n) {
                float xk = __shfl(zr[n][c], k2);
                u[n][0] = fmaf(xk, w0, u[n][0]);
                u[n][1] = fmaf(xk, w1, u[n][1]);
            }
        }
    }
#pragma unroll
    for (int n = 0; n < 4; ++n) {
        u[n][0] = u[n][0] > 0.f ? u[n][0] : 0.f;
        u[n][1] = u[n][1] > 0.f ? u[n][1] : 0.f;
    }
    // matmul 2: z3 = u@aW2 + ab2 + h_gcn
    float c20 = ab2[l], c21 = ab2[64 + l];
    float z3[4][2];
#pragma unroll
    for (int n = 0; n < 4; ++n) { z3[n][0] = c20; z3[n][1] = c21; }
#pragma unroll
    for (int c = 0; c < 2; ++c) {
#pragma unroll 8
        for (int k2 = 0; k2 < 64; ++k2) {
            int k = c * 64 + k2;
            float w0 = aW2[k * 128 + l], w1 = aW2[k * 128 + 64 + l];
#pragma unroll
            for (int n = 0; n < 4; ++n) {
                float xk = __shfl(u[n][c], k2);
                z3[n][0] = fmaf(xk, w0, z3[n][0]);
                z3[n][1] = fmaf(xk, w1, z3[n][1]);
            }
        }
    }
#pragma unroll
    for (int n = 0; n < 4; ++n) if (n < nn) {
        int i = i0 + n;
        z3[n][0] += h_gcn[(size_t)i * 128 + l];
        z3[n][1] += h_gcn[(size_t)i * 128 + 64 + l];
    }
    // matmul 3: d = z3@Wo + bo
    float c30 = bo[l], c31 = bo[64 + l];
    float ac[4][2];
#pragma unroll
    for (int n = 0; n < 4; ++n) { ac[n][0] = c30; ac[n][1] = c31; }
#pragma unroll
    for (int c = 0; c < 2; ++c) {
#pragma unroll 8
        for (int k2 = 0; k2 < 64; ++k2) {
            int k = c * 64 + k2;
            float w0 = Wo[k * 128 + l], w1 = Wo[k * 128 + 64 + l];
#pragma unroll
            for (int n = 0; n < 4; ++n) {
                float xk = __shfl(z3[n][c], k2);
                ac[n][0] = fmaf(xk, w0, ac[n][0]);
                ac[n][1] = fmaf(xk, w1, ac[n][1]);
            }
        }
    }
    float g0 = g[l], g1 = g[64 + l], bb0 = b[l], bb1 = b[64 + l];
#pragma unroll
    for (int n = 0; n < 4; ++n) if (n < nn) {
        int i = i0 + n;
        float v0 = ac[n][0] + x[(size_t)i * 128 + l];
        float v1 = ac[n][1] + x[(size_t)i * 128 + 64 + l];
        float m = wredsum(v0 + v1) * 0.0078125f;
        float d0 = v0 - m, d1 = v1 - m;
        float r = rsqrtf(wredsum(d0 * d0 + d1 * d1) * 0.0078125f + 1e-5f);
        obr[(size_t)i * 128 + l]      = d0 * r * g0 + bb0;
        obr[(size_t)i * 128 + 64 + l] = d1 * r * g1 + bb1;
    }
}

// ---------------- temporal epilogue, 4 nodes/wave ----------------
__global__ __launch_bounds__(256) void k_ep_tmpB(const float* __restrict__ h_tmp,
                                                 const float* __restrict__ agg,
                                                 const float* __restrict__ Wo,
                                                 const float* __restrict__ bo,
                                                 const float* __restrict__ g,
                                                 const float* __restrict__ b,
                                                 float* __restrict__ obr, int N) {
    int l = threadIdx.x & 63;
    int i0 = (blockIdx.x * 4 + (threadIdx.x >> 6)) * 4;
    if (i0 >= N) return;
    int nn = N - i0; if (nn > 4) nn = 4;
    float zr[4][2];
#pragma unroll
    for (int n = 0; n < 4; ++n) {
        int i = i0 + (n < nn ? n : 0);
        zr[n][0] = h_tmp[(size_t)i * 128 + l]      + agg[(size_t)i * 128 + l];
        zr[n][1] = h_tmp[(size_t)i * 128 + 64 + l] + agg[(size_t)i * 128 + 64 + l];
    }
    float b0 = bo[l], b1v = bo[64 + l];
    float ac[4][2];
#pragma unroll
    for (int n = 0; n < 4; ++n) { ac[n][0] = b0; ac[n][1] = b1v; }
#pragma unroll
    for (int c = 0; c < 2; ++c) {
#pragma unroll 8
        for (int k2 = 0; k2 < 64; ++k2) {
            int k = c * 64 + k2;
            float w0 = Wo[k * 128 + l], w1 = Wo[k * 128 + 64 + l];
#pragma unroll
            for (int n = 0; n < 4; ++n) {
                float xk = __shfl(zr[n][c], k2);
                ac[n][0] = fmaf(xk, w0, ac[n][0]);
                ac[n][1] = fmaf(xk, w1, ac[n][1]);
            }
        }
    }
    float g0 = g[l], g1 = g[64 + l], bb0 = b[l], bb1 = b[64 + l];
#pragma unroll
    for (int n = 0; n < 4; ++n) if (n < nn) {
        int i = i0 + n;
        float v0 = ac[n][0], v1 = ac[n][1];
        float m = wredsum(v0 + v1) * 0.0078125f;
        float d0 = v0 - m, d1 = v1 - m;
        float r = rsqrtf(wredsum(d0 * d0 + d1 * d1) * 0.0078125f + 1e-5f);
        obr[(size_t)i * 128 + l]      = d0 * r * g0 + bb0;
        obr[(size_t)i * 128 + 64 + l] = d1 * r * g1 + bb1;
    }
}

// ---------------- fusion accumulate, 4 nodes/wave ----------------
__global__ __launch_bounds__(256) void k_fuseB(const float* __restrict__ obr,
                                               const float* __restrict__ fusW,
                                               const float* __restrict__ fus_b,
                                               float* __restrict__ fused,
                                               int off, int first, int N) {
    int l = threadIdx.x & 63;
    int i0 = (blockIdx.x * 4 + (threadIdx.x >> 6)) * 4;
    if (i0 >= N) return;
    int nn = N - i0; if (nn > 4) nn = 4;
    float zr[4][2];
#pragma unroll
    for (int n = 0; n < 4; ++n) {
        int i = i0 + (n < nn ? n : 0);
        zr[n][0] = obr[(size_t)i * 128 + l];
        zr[n][1] = obr[(size_t)i * 128 + 64 + l];
    }
    float fb0 = fus_b[l], fb1 = fus_b[64 + l];
    float ac[4][2];
#pragma unroll
    for (int n = 0; n < 4; ++n) {
        int i = i0 + (n < nn ? n : 0);
        ac[n][0] = first ? fb0 : fused[(size_t)i * 128 + l];
        ac[n][1] = first ? fb1 : fused[(size_t)i * 128 + 64 + l];
    }
    const float* W = fusW + (size_t)off * 128;
#pragma unroll
    for (int c = 0; c < 2; ++c) {
#pragma unroll 8
        for (int k2 = 0; k2 < 64; ++k2) {
            int k = c * 64 + k2;
            float w0 = W[(size_t)k * 128 + l], w1 = W[(size_t)k * 128 + 64 + l];
#pragma unroll
            for (int n = 0; n < 4; ++n) {
                float xk = __shfl(zr[n][c], k2);
                ac[n][0] = fmaf(xk, w0, ac[n][0]);
                ac[n][1] = fmaf(xk, w1, ac[n][1]);
            }
        }
    }
#pragma unroll
    for (int n = 0; n < 4; ++n) if (n < nn) {
        int i = i0 + n;
        fused[(size_t)i * 128 + l]      = ac[n][0];
        fused[(size_t)i * 128 + 64 + l] = ac[n][1];
    }
}

// ---------------- final LN, 4 nodes/wave ----------------
__global__ __launch_bounds__(256) void k_finalB(const float* __restrict__ fused,
                                                const float* __restrict__ g,
                                                const float* __restrict__ b,
                                                float* __restrict__ out, int N) {
    int l = threadIdx.x & 63;
    int i0 = (blockIdx.x * 4 + (threadIdx.x >> 6)) * 4;
    if (i0 >= N) return;
    int nn = N - i0; if (nn > 4) nn = 4;
    float g0 = g[l], g1 = g[64 + l], bb0 = b[l], bb1 = b[64 + l];
#pragma unroll
    for (int n = 0; n < 4; ++n) if (n < nn) {
        int i = i0 + n;
        float v0 = fused[(size_t)i * 128 + l];
        float v1 = fused[(size_t)i * 128 + 64 + l];
        float m = wredsum(v0 + v1) * 0.0078125f;
        float d0 = v0 - m, d1 = v1 - m;
        float r = rsqrtf(wredsum(d0 * d0 + d1 * d1) * 0.0078125f + 1e-5f);
        out[(size_t)i * 128 + l]      = d0 * r * g0 + bb0;
        out[(size_t)i * 128 + 64 + l] = d1 * r * g1 + bb1;
    }
}

extern "C" void kernel_launch(void* const* d_in, const int* in_sizes, int n_in, void* d_out,
                              int out_size, void* d_ws, size_t ws_size, hipStream_t stream) {
    (void)n_in; (void)out_size; (void)ws_size;
    const float* x = (const float*)d_in[0];
    const float* gat_Wq = (const float*)d_in[4];
    const float* gat_Wk = (const float*)d_in[5];
    const float* gat_Wv = (const float*)d_in[6];
    const float* gat_Wo = (const float*)d_in[7];
    const float* gat_bo = (const float*)d_in[8];
    const float* gat_g = (const float*)d_in[9];
    const float* gat_b = (const float*)d_in[10];
    const float* gcn_Wt = (const float*)d_in[11];
    const float* gcn_bt = (const float*)d_in[12];
    const float* gcn_mW1 = (const float*)d_in[13];
    const float* gcn_mb1 = (const float*)d_in[14];
    const float* gcn_mW2 = (const float*)d_in[15];
    const float* gcn_mb2 = (const float*)d_in[16];
    const float* gcn_aW1 = (const float*)d_in[17];
    const float* gcn_ab1 = (const float*)d_in[18];
    const float* gcn_aW2 = (const float*)d_in[19];
    const float* gcn_ab2 = (const float*)d_in[20];
    const float* gcn_Wo = (const float*)d_in[21];
    const float* gcn_bo = (const float*)d_in[22];
    const float* gcn_g = (const float*)d_in[23];
    const float* gcn_b = (const float*)d_in[24];
    const float* tmp_emb = (const float*)d_in[25];
    const float* tmp_W1 = (const float*)d_in[26];
    const float* tmp_b1 = (const float*)d_in[27];
    const float* tmp_W2 = (const float*)d_in[28];
    const float* tmp_b2 = (const float*)d_in[29];
    const float* tmp_Wo = (const float*)d_in[30];
    const float* tmp_bo = (const float*)d_in[31];
    const float* tmp_g = (const float*)d_in[32];
    const float* tmp_b = (const float*)d_in[33];
    const float* fus_W = (const float*)d_in[34];
    const float* fus_b = (const float*)d_in[35];
    const float* fus_g = (const float*)d_in[36];
    const float* fus_be = (const float*)d_in[37];

    int N = in_sizes[0] / 128;
    int E = in_sizes[1] / 2;

    // ---- workspace ----
    float* ws = (float*)d_ws;
    float* big = ws;                          // [0,384N): QKV during GAT phase
    float* fused = ws;                        // [0,128N): alias after QKV dead
    float* h_gcn = ws + (size_t)128 * N;      // [128N,256N)
    float* h_tmp = ws + (size_t)256 * N;      // [256N,384N)
    float* obr = ws + (size_t)384 * N;        // [384N,512N)
    float* agg = ws + (size_t)512 * N;        // [512N,640N)
    float* sm = ws + (size_t)640 * N;         // [640N,648N)
    u32* flags = (u32*)(ws + (size_t)648 * N);
    int* ei32 = (int*)(flags + 16);
    int* nt32 = ei32 + (size_t)2 * E;
    int* tp32 = nt32 + N;
    float* scores = (float*)(tp32 + N);       // E*8 floats

    // Pa/Pb live in slots that are dead during each mlp phase:
    // GCN phase:  Pa @ [256N,384N) (h_tmp slot, not yet written), Pb @ [384N,512N) (obr dead)
    // TMP phase:  Pa @ [128N,256N) (h_gcn dead),                  Pb @ [384N,512N) (obr dead)
    float* Pa_gcn = ws + (size_t)256 * N;
    float* Pb_gcn = ws + (size_t)384 * N;
    float* Pa_tmp = ws + (size_t)128 * N;
    float* Pb_tmp = ws + (size_t)384 * N;

    // ---- index canonicalization (planar (2,E) layout) ----
    k_detect13<<<1, 64, 0, stream>>>((const u32*)d_in[1], (const u32*)d_in[2],
                                     (const u32*)d_in[3], flags);
    long long nEI = (long long)2 * E;
    k_cvt13<<<(int)((nEI + 255) / 256), 256, 0, stream>>>(d_in[1], ei32, nEI, flags, 0);
    k_cvt13<<<(N + 255) / 256, 256, 0, stream>>>(d_in[2], nt32, N, flags, 1);
    k_cvt13<<<(N + 255) / 256, 256, 0, stream>>>(d_in[3], tp32, N, flags, 2);

    long long nAgg = (long long)128 * N, nAggSm = (long long)136 * N;
    int gAggSm = (int)((nAggSm + 255) / 256), gAgg = (int)((nAgg + 255) / 256);
    int gE8 = (int)(((long long)E * 8 + 255) / 256);
    int gE128 = (int)(((long long)E * 128 + 255) / 256);
    int gN128 = (int)(((long long)N * 128 + 255) / 256);
    int gB = (N + 15) / 16;  // 4 waves x 4 nodes per 256-thread block

    // ===== GAT branch =====
    kz13<<<gAggSm, 256, 0, stream>>>(agg, nAggSm);                   // zero agg + sm
    k_qkvB<<<gB, 256, 0, stream>>>(x, gat_Wq, gat_Wk, gat_Wv, big, N);
    k_gat_smB<<<gE8, 256, 0, stream>>>(big, ei32, E, scores, sm);
    k_gat_wv13<<<gE128, 256, 0, stream>>>(big, ei32, E, scores, sm, agg);
    k_ep_gatB<<<gB, 256, 0, stream>>>(x, agg, gat_Wo, gat_bo, gat_g, gat_b, obr, N);
    k_fuseB<<<gB, 256, 0, stream>>>(obr, fus_W, fus_b, fused, 0, 1, N);  // QKV dead

    // ===== GCN branch =====
    k_hgcn13<<<N, 64, 0, stream>>>(x, nt32, gcn_Wt, gcn_bt, h_gcn);
    kz13<<<gAgg, 256, 0, stream>>>(agg, nAgg);
    k_preB<<<gB, 256, 0, stream>>>(h_gcn, gcn_mW1, gcn_mb1, Pa_gcn, Pb_gcn, N);
    k_mlp2<<<512, 512, 0, stream>>>(Pa_gcn, Pb_gcn, ei32, E, gcn_mW2, gcn_mb2, agg);
    k_ep_gcnB<<<gB, 256, 0, stream>>>(x, h_gcn, agg, gcn_aW1, gcn_ab1, gcn_aW2, gcn_ab2,
                                      gcn_Wo, gcn_bo, gcn_g, gcn_b, obr, N);
    k_fuseB<<<gB, 256, 0, stream>>>(obr, fus_W, fus_b, fused, 128, 0, N);

    // ===== temporal branch =====
    k_htmp13<<<gN128, 256, 0, stream>>>(x, tmp_emb, tp32, h_tmp, N);
    kz13<<<gAgg, 256, 0, stream>>>(agg, nAgg);
    k_preB<<<gB, 256, 0, stream>>>(h_tmp, tmp_W1, tmp_b1, Pa_tmp, Pb_tmp, N);
    k_mlp2<<<512, 512, 0, stream>>>(Pa_tmp, Pb_tmp, ei32, E, tmp_W2, tmp_b2, agg);
    k_ep_tmpB<<<gB, 256, 0, stream>>>(h_tmp, agg, tmp_Wo, tmp_bo, tmp_g, tmp_b, obr, N);
    k_fuseB<<<gB, 256, 0, stream>>>(obr, fus_W, fus_b, fused, 256, 0, N);

    // ===== final (float32 output) =====
    k_finalB<<<gB, 256, 0, stream>>>(fused, fus_g, fus_be, (float*)d_out, N);
}

// Round 2
// 738.663 us; speedup vs baseline: 1.7917x; 1.7917x over previous
//
#include <hip/hip_runtime.h>

using u32 = unsigned int;
using s64 = long long;

// -------- int width detection (int64 iff hi-words of first 64 entries all 0) --------
__global__ __launch_bounds__(64) void k_detect13(const u32* __restrict__ ei,
                                                 const u32* __restrict__ nt,
                                                 const u32* __restrict__ tp,
                                                 u32* __restrict__ flags) {
    if (blockIdx.x != 0 || threadIdx.x != 0) return;
    bool e64 = true, n64 = true, t64 = true;
    for (int k = 0; k < 64; ++k) {
        if (ei[2 * k + 1] != 0u) e64 = false;
        if (nt[2 * k + 1] != 0u) n64 = false;
        if (tp[2 * k + 1] != 0u) t64 = false;
    }
    flags[0] = e64 ? 1u : 0u;
    flags[1] = n64 ? 1u : 0u;
    flags[2] = t64 ? 1u : 0u;
}

// -------- width-adaptive convert to int32 --------
__global__ __launch_bounds__(256) void k_cvt13(const void* __restrict__ src,
                                               int* __restrict__ dst, long long n,
                                               const u32* __restrict__ flags, int fidx) {
    long long i = (long long)blockIdx.x * 256 + threadIdx.x;
    if (i >= n) return;
    dst[i] = flags[fidx] ? (int)((const s64*)src)[i] : ((const int*)src)[i];
}

// ---------------- zero (float / int) ----------------
__global__ __launch_bounds__(256) void kz13(float* __restrict__ p, long long n) {
    long long i = (long long)blockIdx.x * 256 + threadIdx.x;
    if (i < n) p[i] = 0.f;
}
__global__ __launch_bounds__(256) void kz_i(int* __restrict__ p, int n) {
    int i = blockIdx.x * 256 + threadIdx.x;
    if (i < n) p[i] = 0;
}

// ---------------- counting sort by col ----------------
__global__ __launch_bounds__(256) void k_hist(const int* __restrict__ ei, int E,
                                              int* __restrict__ cnt) {
    int e = blockIdx.x * 256 + threadIdx.x;
    if (e < E) atomicAdd(&cnt[ei[E + e]], 1);
}

__global__ __launch_bounds__(1024) void k_scan(const int* __restrict__ cnt,
                                               int* __restrict__ offA, int N) {
    __shared__ int part[1024];
    int t = threadIdx.x;
    int C = (N + 1023) >> 10;
    int beg = t * C, end = beg + C; if (end > N) end = N;
    int s = 0;
    for (int k = beg; k < end; ++k) s += cnt[k];
    part[t] = s; __syncthreads();
    for (int o = 1; o < 1024; o <<= 1) {
        int v = (t >= o) ? part[t - o] : 0;
        __syncthreads();
        part[t] += v;
        __syncthreads();
    }
    int base = (t == 0) ? 0 : part[t - 1];
    for (int k = beg; k < end; ++k) { offA[k] = base; base += cnt[k]; }
    if (t == 1023) offA[N] = part[1023];
}

__global__ __launch_bounds__(256) void k_scatter(const int* __restrict__ ei, int E,
                                                 const int* __restrict__ offA,
                                                 int* __restrict__ cur,
                                                 int* __restrict__ srow,
                                                 int* __restrict__ sedge) {
    int e = blockIdx.x * 256 + threadIdx.x;
    if (e >= E) return;
    int col = ei[E + e];
    int p = offA[col] + atomicAdd(&cur[col], 1);
    srow[p] = ei[e];
    sedge[p] = e;
}

// wave-wide sum over 64 lanes
__device__ __forceinline__ float wredsum(float v) {
#pragma unroll
    for (int o = 32; o; o >>= 1) v += __shfl_xor(v, o);
    return v;
}

// out += in @ W  (W row-major 128x128); lane l owns cols l, 64+l; 4 nodes/wave
__device__ __forceinline__ void mm4(const float (&in)[4][2], float (&out)[4][2],
                                    const float* __restrict__ W, int l) {
#pragma unroll
    for (int c = 0; c < 2; ++c)
#pragma unroll 8
        for (int k2 = 0; k2 < 64; ++k2) {
            int k = c * 64 + k2;
            float w0 = W[(size_t)k * 128 + l], w1 = W[(size_t)k * 128 + 64 + l];
#pragma unroll
            for (int n = 0; n < 4; ++n) {
                float xk = __shfl(in[n][c], k2);
                out[n][0] = fmaf(xk, w0, out[n][0]);
                out[n][1] = fmaf(xk, w1, out[n][1]);
            }
        }
}

// ---------------- QKV: 4 nodes per wave, shfl-broadcast x ----------------
__global__ __launch_bounds__(256) void k_qkvB(const float* __restrict__ x,
                                              const float* __restrict__ Wq,
                                              const float* __restrict__ Wk,
                                              const float* __restrict__ Wv,
                                              float* __restrict__ big, int N) {
    int l = threadIdx.x & 63;
    int i0 = (blockIdx.x * 4 + (threadIdx.x >> 6)) * 4;
    if (i0 >= N) return;
    int nn = N - i0; if (nn > 4) nn = 4;
    float zr[4][2];
#pragma unroll
    for (int n = 0; n < 4; ++n) {
        int i = i0 + (n < nn ? n : 0);
        zr[n][0] = x[(size_t)i * 128 + l];
        zr[n][1] = x[(size_t)i * 128 + 64 + l];
    }
    float aq[4][2], ak[4][2], av[4][2];
#pragma unroll
    for (int n = 0; n < 4; ++n) {
        aq[n][0] = aq[n][1] = ak[n][0] = ak[n][1] = av[n][0] = av[n][1] = 0.f;
    }
#pragma unroll
    for (int c = 0; c < 2; ++c) {
#pragma unroll 8
        for (int k2 = 0; k2 < 64; ++k2) {
            int k = c * 64 + k2;
            float wq0 = Wq[k * 128 + l], wq1 = Wq[k * 128 + 64 + l];
            float wk0 = Wk[k * 128 + l], wk1 = Wk[k * 128 + 64 + l];
            float wv0 = Wv[k * 128 + l], wv1 = Wv[k * 128 + 64 + l];
#pragma unroll
            for (int n = 0; n < 4; ++n) {
                float xk = __shfl(zr[n][c], k2);
                aq[n][0] = fmaf(xk, wq0, aq[n][0]); aq[n][1] = fmaf(xk, wq1, aq[n][1]);
                ak[n][0] = fmaf(xk, wk0, ak[n][0]); ak[n][1] = fmaf(xk, wk1, ak[n][1]);
                av[n][0] = fmaf(xk, wv0, av[n][0]); av[n][1] = fmaf(xk, wv1, av[n][1]);
            }
        }
    }
#pragma unroll
    for (int n = 0; n < 4; ++n) if (n < nn) {
        size_t b = (size_t)(i0 + n) * 384;
        big[b + l] = aq[n][0];        big[b + 64 + l] = aq[n][1];
        big[b + 128 + l] = ak[n][0];  big[b + 192 + l] = ak[n][1];
        big[b + 256 + l] = av[n][0];  big[b + 320 + l] = av[n][1];
    }
}

// ---------------- GAT scores (float4 gathers): exp + segment denominator ----------------
__global__ __launch_bounds__(256) void k_gat_smB(const float* __restrict__ big,
                                                 const int* __restrict__ ei, int E,
                                                 float* __restrict__ scores,
                                                 float* __restrict__ sm) {
    long long t = (long long)blockIdx.x * 256 + threadIdx.x;
    if (t >= (long long)E * 8) return;
    int e = (int)(t >> 3), h = (int)(t & 7);
    int row = ei[e], col = ei[E + e];
    const float4* q = (const float4*)(big + (size_t)row * 384 + h * 16);
    const float4* kk = (const float4*)(big + (size_t)col * 384 + 128 + h * 16);
    float s = 0.f;
#pragma unroll
    for (int d = 0; d < 4; ++d) {
        float4 a = q[d], b = kk[d];
        s += a.x * b.x + a.y * b.y + a.z * b.z + a.w * b.w;
    }
    s *= 0.25f;
    s = s > 0.f ? s : 0.2f * s;
    float ex = expf(s);
    scores[t] = ex;
    atomicAdd(&sm[(size_t)col * 8 + h], ex);
}

// ------- GAT weighted-V, sorted segments: one wave per col, no atomics -------
__global__ __launch_bounds__(256) void k_wvS(const float* __restrict__ big,
                                             const float* __restrict__ scores,
                                             const float* __restrict__ sm,
                                             const int* __restrict__ srow,
                                             const int* __restrict__ sedge,
                                             const int* __restrict__ offA,
                                             float* __restrict__ agg, int N) {
    int l = threadIdx.x & 63;
    int col = blockIdx.x * 4 + (threadIdx.x >> 6);
    if (col >= N) return;
    int hh = l >> 4;
    float s0 = sm[(size_t)col * 8 + hh], s1 = sm[(size_t)col * 8 + 4 + hh];
    float ism0 = s0 != 0.f ? 1.f / s0 : 0.f;
    float ism1 = s1 != 0.f ? 1.f / s1 : 0.f;
    float a0 = 0.f, a1 = 0.f;
    int p = offA[col], pe = offA[col + 1];
    for (; p + 2 <= pe; p += 2) {
        int e0 = sedge[p], r0 = srow[p], e1 = sedge[p + 1], r1 = srow[p + 1];
        float pr00 = scores[(size_t)e0 * 8 + hh] * ism0;
        float pr01 = scores[(size_t)e0 * 8 + 4 + hh] * ism1;
        float pr10 = scores[(size_t)e1 * 8 + hh] * ism0;
        float pr11 = scores[(size_t)e1 * 8 + 4 + hh] * ism1;
        a0 += pr00 * big[(size_t)r0 * 384 + 256 + l] + pr10 * big[(size_t)r1 * 384 + 256 + l];
        a1 += pr01 * big[(size_t)r0 * 384 + 320 + l] + pr11 * big[(size_t)r1 * 384 + 320 + l];
    }
    for (; p < pe; ++p) {
        int e = sedge[p], r = srow[p];
        a0 += scores[(size_t)e * 8 + hh] * ism0 * big[(size_t)r * 384 + 256 + l];
        a1 += scores[(size_t)e * 8 + 4 + hh] * ism1 * big[(size_t)r * 384 + 320 + l];
    }
    agg[(size_t)col * 128 + l] = a0;
    agg[(size_t)col * 128 + 64 + l] = a1;
}

// ---- GAT epilogue + fusion fold: fused = LN(agg@Wo+bo+x) @ fusW[0:128] + fus_b ----
__global__ __launch_bounds__(256) void k_ep_gatF(const float* __restrict__ x,
                                                 const float* __restrict__ agg,
                                                 const float* __restrict__ Wo,
                                                 const float* __restrict__ bo,
                                                 const float* __restrict__ g,
                                                 const float* __restrict__ b,
                                                 const float* __restrict__ fusW,
                                                 const float* __restrict__ fus_b,
                                                 float* __restrict__ fused, int N) {
    int l = threadIdx.x & 63;
    int i0 = (blockIdx.x * 4 + (threadIdx.x >> 6)) * 4;
    if (i0 >= N) return;
    int nn = N - i0; if (nn > 4) nn = 4;
    float zr[4][2], ac[4][2];
    float b0 = bo[l], b1 = bo[64 + l];
#pragma unroll
    for (int n = 0; n < 4; ++n) {
        int i = i0 + (n < nn ? n : 0);
        zr[n][0] = agg[(size_t)i * 128 + l];
        zr[n][1] = agg[(size_t)i * 128 + 64 + l];
        ac[n][0] = b0; ac[n][1] = b1;
    }
    mm4(zr, ac, Wo, l);
    float g0 = g[l], g1 = g[64 + l], bb0 = b[l], bb1 = b[64 + l];
    float o[4][2];
#pragma unroll
    for (int n = 0; n < 4; ++n) {
        int i = i0 + (n < nn ? n : 0);
        float v0 = ac[n][0] + x[(size_t)i * 128 + l];
        float v1 = ac[n][1] + x[(size_t)i * 128 + 64 + l];
        float m = wredsum(v0 + v1) * 0.0078125f;
        float d0 = v0 - m, d1 = v1 - m;
        float r = rsqrtf(wredsum(d0 * d0 + d1 * d1) * 0.0078125f + 1e-5f);
        o[n][0] = d0 * r * g0 + bb0;
        o[n][1] = d1 * r * g1 + bb1;
    }
    float f0 = fus_b[l], f1 = fus_b[64 + l];
    float ac2[4][2];
#pragma unroll
    for (int n = 0; n < 4; ++n) { ac2[n][0] = f0; ac2[n][1] = f1; }
    mm4(o, ac2, fusW, l);
#pragma unroll
    for (int n = 0; n < 4; ++n) if (n < nn) {
        int i = i0 + n;
        fused[(size_t)i * 128 + l]      = ac2[n][0];
        fused[(size_t)i * 128 + 64 + l] = ac2[n][1];
    }
}

// ---------------- per-type transform, 4 nodes/wave ----------------
__global__ __launch_bounds__(256) void k_hgcnB(const float* __restrict__ x,
                                               const int* __restrict__ nt,
                                               const float* __restrict__ Wt,
                                               const float* __restrict__ bt,
                                               float* __restrict__ h_gcn, int N) {
    int l = threadIdx.x & 63;
    int i0 = (blockIdx.x * 4 + (threadIdx.x >> 6)) * 4;
    if (i0 >= N) return;
    int nn = N - i0; if (nn > 4) nn = 4;
    const float* W[4];
    float ac[4][2], zr[4][2];
#pragma unroll
    for (int n = 0; n < 4; ++n) {
        int i = i0 + (n < nn ? n : 0);
        int t = nt[i]; t = (t < 0 || t > 5) ? 0 : t;
        W[n] = Wt + (size_t)t * 16384;
        ac[n][0] = bt[t * 128 + l]; ac[n][1] = bt[t * 128 + 64 + l];
        zr[n][0] = x[(size_t)i * 128 + l];
        zr[n][1] = x[(size_t)i * 128 + 64 + l];
    }
#pragma unroll
    for (int c = 0; c < 2; ++c)
#pragma unroll 4
        for (int k2 = 0; k2 < 64; ++k2) {
            int k = c * 64 + k2;
#pragma unroll
            for (int n = 0; n < 4; ++n) {
                float w0 = W[n][k * 128 + l], w1 = W[n][k * 128 + 64 + l];
                float xk = __shfl(zr[n][c], k2);
                ac[n][0] = fmaf(xk, w0, ac[n][0]);
                ac[n][1] = fmaf(xk, w1, ac[n][1]);
            }
        }
#pragma unroll
    for (int n = 0; n < 4; ++n) if (n < nn) {
        int i = i0 + n;
        h_gcn[(size_t)i * 128 + l]      = ac[n][0];
        h_gcn[(size_t)i * 128 + 64 + l] = ac[n][1];
    }
}

// ---------------- h_tmp = x + emb[clip(tpos)] ----------------
__global__ __launch_bounds__(256) void k_htmp13(const float* __restrict__ x,
                                                const float* __restrict__ emb,
                                                const int* __restrict__ tpos,
                                                float* __restrict__ h_tmp, int N) {
    long long t = (long long)blockIdx.x * 256 + threadIdx.x;
    if (t >= (long long)N * 128) return;
    int i = (int)(t >> 7), j = (int)(t & 127);
    int tp = tpos[i]; tp = tp < 0 ? 0 : (tp > 49 ? 49 : tp);
    h_tmp[t] = x[t] + emb[tp * 128 + j];
}

// ------- layer-1 precompute: Pa = h@W1[0:128], Pb = h@W1[128:256] + b1 -------
__global__ __launch_bounds__(256) void k_preB(const float* __restrict__ h,
                                              const float* __restrict__ W1,
                                              const float* __restrict__ b1,
                                              float* __restrict__ Pa,
                                              float* __restrict__ Pb, int N) {
    int l = threadIdx.x & 63;
    int i0 = (blockIdx.x * 4 + (threadIdx.x >> 6)) * 4;
    if (i0 >= N) return;
    int nn = N - i0; if (nn > 4) nn = 4;
    float zr[4][2];
#pragma unroll
    for (int n = 0; n < 4; ++n) {
        int i = i0 + (n < nn ? n : 0);
        zr[n][0] = h[(size_t)i * 128 + l];
        zr[n][1] = h[(size_t)i * 128 + 64 + l];
    }
    float bb0 = b1[l], bb1 = b1[64 + l];
    float aa[4][2], ab[4][2];
#pragma unroll
    for (int n = 0; n < 4; ++n) { aa[n][0] = aa[n][1] = 0.f; ab[n][0] = bb0; ab[n][1] = bb1; }
#pragma unroll
    for (int c = 0; c < 2; ++c) {
#pragma unroll 8
        for (int k2 = 0; k2 < 64; ++k2) {
            int k = c * 64 + k2;
            float wa0 = W1[k * 128 + l],           wa1 = W1[k * 128 + 64 + l];
            float wb0 = W1[(k + 128) * 128 + l],   wb1 = W1[(k + 128) * 128 + 64 + l];
#pragma unroll
            for (int n = 0; n < 4; ++n) {
                float xk = __shfl(zr[n][c], k2);
                aa[n][0] = fmaf(xk, wa0, aa[n][0]); aa[n][1] = fmaf(xk, wa1, aa[n][1]);
                ab[n][0] = fmaf(xk, wb0, ab[n][0]); ab[n][1] = fmaf(xk, wb1, ab[n][1]);
            }
        }
    }
#pragma unroll
    for (int n = 0; n < 4; ++n) if (n < nn) {
        size_t o = (size_t)(i0 + n) * 128;
        Pa[o + l] = aa[n][0]; Pa[o + 64 + l] = aa[n][1];
        Pb[o + l] = ab[n][0]; Pb[o + 64 + l] = ab[n][1];
    }
}

// ------- relu-sum over sorted segment: s[col] = sum_e relu(Pa[row_e]+Pb[col]) -------
__global__ __launch_bounds__(256) void k_rsum(const float* __restrict__ Pa,
                                              const float* __restrict__ Pb,
                                              const int* __restrict__ srow,
                                              const int* __restrict__ offA,
                                              float* __restrict__ s, int N) {
    int l = threadIdx.x & 63;
    int col = blockIdx.x * 4 + (threadIdx.x >> 6);
    if (col >= N) return;
    float pb0 = Pb[(size_t)col * 128 + l], pb1 = Pb[(size_t)col * 128 + 64 + l];
    float a0 = 0.f, a1 = 0.f;
    int p = offA[col], pe = offA[col + 1];
    for (; p + 4 <= pe; p += 4) {
        int r0 = srow[p], r1 = srow[p + 1], r2 = srow[p + 2], r3 = srow[p + 3];
        float x00 = Pa[(size_t)r0 * 128 + l], x01 = Pa[(size_t)r0 * 128 + 64 + l];
        float x10 = Pa[(size_t)r1 * 128 + l], x11 = Pa[(size_t)r1 * 128 + 64 + l];
        float x20 = Pa[(size_t)r2 * 128 + l], x21 = Pa[(size_t)r2 * 128 + 64 + l];
        float x30 = Pa[(size_t)r3 * 128 + l], x31 = Pa[(size_t)r3 * 128 + 64 + l];
        a0 += fmaxf(x00 + pb0, 0.f) + fmaxf(x10 + pb0, 0.f)
            + fmaxf(x20 + pb0, 0.f) + fmaxf(x30 + pb0, 0.f);
        a1 += fmaxf(x01 + pb1, 0.f) + fmaxf(x11 + pb1, 0.f)
            + fmaxf(x21 + pb1, 0.f) + fmaxf(x31 + pb1, 0.f);
    }
    for (; p < pe; ++p) {
        int r = srow[p];
        a0 += fmaxf(Pa[(size_t)r * 128 + l] + pb0, 0.f);
        a1 += fmaxf(Pa[(size_t)r * 128 + 64 + l] + pb1, 0.f);
    }
    s[(size_t)col * 128 + l] = a0;
    s[(size_t)col * 128 + 64 + l] = a1;
}

// ---- GCN epilogue + W2 fold + fusion fold (5 chained matmuls) ----
__global__ __launch_bounds__(256) void k_ep_gcnF(const float* __restrict__ x,
                                                 const float* __restrict__ h_gcn,
                                                 const float* __restrict__ s,
                                                 const int* __restrict__ offA,
                                                 const float* __restrict__ W2,
                                                 const float* __restrict__ b2,
                                                 const float* __restrict__ aW1,
                                                 const float* __restrict__ ab1,
                                                 const float* __restrict__ aW2,
                                                 const float* __restrict__ ab2,
                                                 const float* __restrict__ Wo,
                                                 const float* __restrict__ bo,
                                                 const float* __restrict__ g,
                                                 const float* __restrict__ b,
                                                 const float* __restrict__ fusW,
                                                 float* __restrict__ fused, int N) {
    int l = threadIdx.x & 63;
    int i0 = (blockIdx.x * 4 + (threadIdx.x >> 6)) * 4;
    if (i0 >= N) return;
    int nn = N - i0; if (nn > 4) nn = 4;
    float zr[4][2], t1[4][2];
    float b20 = b2[l], b21 = b2[64 + l];
#pragma unroll
    for (int n = 0; n < 4; ++n) {
        int i = i0 + (n < nn ? n : 0);
        zr[n][0] = s[(size_t)i * 128 + l];
        zr[n][1] = s[(size_t)i * 128 + 64 + l];
        float deg = (float)(offA[i + 1] - offA[i]);
        t1[n][0] = deg * b20; t1[n][1] = deg * b21;
    }
    mm4(zr, t1, W2, l);                       // t1 = agg = s@W2 + deg*b2
    float u[4][2];
    float a10 = ab1[l], a11 = ab1[64 + l];
#pragma unroll
    for (int n = 0; n < 4; ++n) { u[n][0] = a10; u[n][1] = a11; }
    mm4(t1, u, aW1, l);
#pragma unroll
    for (int n = 0; n < 4; ++n) {
        u[n][0] = fmaxf(u[n][0], 0.f);
        u[n][1] = fmaxf(u[n][1], 0.f);
    }
    float z3[4][2];
    float a20 = ab2[l], a21 = ab2[64 + l];
#pragma unroll
    for (int n = 0; n < 4; ++n) { z3[n][0] = a20; z3[n][1] = a21; }
    mm4(u, z3, aW2, l);
#pragma unroll
    for (int n = 0; n < 4; ++n) {
        int i = i0 + (n < nn ? n : 0);
        z3[n][0] += h_gcn[(size_t)i * 128 + l];
        z3[n][1] += h_gcn[(size_t)i * 128 + 64 + l];
    }
    float d[4][2];
    float bo0 = bo[l], bo1 = bo[64 + l];
#pragma unroll
    for (int n = 0; n < 4; ++n) { d[n][0] = bo0; d[n][1] = bo1; }
    mm4(z3, d, Wo, l);
    float g0 = g[l], g1 = g[64 + l], bb0 = b[l], bb1 = b[64 + l];
    float o[4][2];
#pragma unroll
    for (int n = 0; n < 4; ++n) {
        int i = i0 + (n < nn ? n : 0);
        float v0 = d[n][0] + x[(size_t)i * 128 + l];
        float v1 = d[n][1] + x[(size_t)i * 128 + 64 + l];
        float m = wredsum(v0 + v1) * 0.0078125f;
        float d0 = v0 - m, d1 = v1 - m;
        float r = rsqrtf(wredsum(d0 * d0 + d1 * d1) * 0.0078125f + 1e-5f);
        o[n][0] = d0 * r * g0 + bb0;
        o[n][1] = d1 * r * g1 + bb1;
    }
    float ac2[4][2];
#pragma unroll
    for (int n = 0; n < 4; ++n) {
        int i = i0 + (n < nn ? n : 0);
        ac2[n][0] = fused[(size_t)i * 128 + l];
        ac2[n][1] = fused[(size_t)i * 128 + 64 + l];
    }
    mm4(o, ac2, fusW + (size_t)128 * 128, l);
#pragma unroll
    for (int n = 0; n < 4; ++n) if (n < nn) {
        int i = i0 + n;
        fused[(size_t)i * 128 + l]      = ac2[n][0];
        fused[(size_t)i * 128 + 64 + l] = ac2[n][1];
    }
}

// ---- temporal epilogue + W2 fold + fusion fold ----
__global__ __launch_bounds__(256) void k_ep_tmpF(const float* __restrict__ h_tmp,
                                                 const float* __restrict__ s,
                                                 const int* __restrict__ offA,
                                                 const float* __restrict__ W2,
                                                 const float* __restrict__ b2,
                                                 const float* __restrict__ Wo,
                                                 const float* __restrict__ bo,
                                                 const float* __restrict__ g,
                                                 const float* __restrict__ b,
                                                 const float* __restrict__ fusW,
                                                 float* __restrict__ fused, int N) {
    int l = threadIdx.x & 63;
    int i0 = (blockIdx.x * 4 + (threadIdx.x >> 6)) * 4;
    if (i0 >= N) return;
    int nn = N - i0; if (nn > 4) nn = 4;
    float zr[4][2], t1[4][2];
    float b20 = b2[l], b21 = b2[64 + l];
#pragma unroll
    for (int n = 0; n < 4; ++n) {
        int i = i0 + (n < nn ? n : 0);
        zr[n][0] = s[(size_t)i * 128 + l];
        zr[n][1] = s[(size_t)i * 128 + 64 + l];
        float deg = (float)(offA[i + 1] - offA[i]);
        t1[n][0] = deg * b20; t1[n][1] = deg * b21;
    }
    mm4(zr, t1, W2, l);                       // t1 = agg
    float z[4][2];
#pragma unroll
    for (int n = 0; n < 4; ++n) {
        int i = i0 + (n < nn ? n : 0);
        z[n][0] = t1[n][0] + h_tmp[(size_t)i * 128 + l];
        z[n][1] = t1[n][1] + h_tmp[(size_t)i * 128 + 64 + l];
    }
    float d[4][2];
    float bo0 = bo[l], bo1 = bo[64 + l];
#pragma unroll
    for (int n = 0; n < 4; ++n) { d[n][0] = bo0; d[n][1] = bo1; }
    mm4(z, d, Wo, l);
    float g0 = g[l], g1 = g[64 + l], bb0 = b[l], bb1 = b[64 + l];
    float o[4][2];
#pragma unroll
    for (int n = 0; n < 4; ++n) {
        float v0 = d[n][0], v1 = d[n][1];
        float m = wredsum(v0 + v1) * 0.0078125f;
        float d0 = v0 - m, d1 = v1 - m;
        float r = rsqrtf(wredsum(d0 * d0 + d1 * d1) * 0.0078125f + 1e-5f);
        o[n][0] = d0 * r * g0 + bb0;
        o[n][1] = d1 * r * g1 + bb1;
    }
    float ac2[4][2];
#pragma unroll
    for (int n = 0; n < 4; ++n) {
        int i = i0 + (n < nn ? n : 0);
        ac2[n][0] = fused[(size_t)i * 128 + l];
        ac2[n][1] = fused[(size_t)i * 128 + 64 + l];
    }
    mm4(o, ac2, fusW + (size_t)256 * 128, l);
#pragma unroll
    for (int n = 0; n < 4; ++n) if (n < nn) {
        int i = i0 + n;
        fused[(size_t)i * 128 + l]      = ac2[n][0];
        fused[(size_t)i * 128 + 64 + l] = ac2[n][1];
    }
}

// ---------------- final LN, 4 nodes/wave ----------------
__global__ __launch_bounds__(256) void k_finalB(const float* __restrict__ fused,
                                                const float* __restrict__ g,
                                                const float* __restrict__ b,
                                                float* __restrict__ out, int N) {
    int l = threadIdx.x & 63;
    int i0 = (blockIdx.x * 4 + (threadIdx.x >> 6)) * 4;
    if (i0 >= N) return;
    int nn = N - i0; if (nn > 4) nn = 4;
    float g0 = g[l], g1 = g[64 + l], bb0 = b[l], bb1 = b[64 + l];
#pragma unroll
    for (int n = 0; n < 4; ++n) if (n < nn) {
        int i = i0 + n;
        float v0 = fused[(size_t)i * 128 + l];
        float v1 = fused[(size_t)i * 128 + 64 + l];
        float m = wredsum(v0 + v1) * 0.0078125f;
        float d0 = v0 - m, d1 = v1 - m;
        float r = rsqrtf(wredsum(d0 * d0 + d1 * d1) * 0.0078125f + 1e-5f);
        out[(size_t)i * 128 + l]      = d0 * r * g0 + bb0;
        out[(size_t)i * 128 + 64 + l] = d1 * r * g1 + bb1;
    }
}

extern "C" void kernel_launch(void* const* d_in, const int* in_sizes, int n_in, void* d_out,
                              int out_size, void* d_ws, size_t ws_size, hipStream_t stream) {
    (void)n_in; (void)out_size; (void)ws_size;
    const float* x = (const float*)d_in[0];
    const float* gat_Wq = (const float*)d_in[4];
    const float* gat_Wk = (const float*)d_in[5];
    const float* gat_Wv = (const float*)d_in[6];
    const float* gat_Wo = (const float*)d_in[7];
    const float* gat_bo = (const float*)d_in[8];
    const float* gat_g = (const float*)d_in[9];
    const float* gat_b = (const float*)d_in[10];
    const float* gcn_Wt = (const float*)d_in[11];
    const float* gcn_bt = (const float*)d_in[12];
    const float* gcn_mW1 = (const float*)d_in[13];
    const float* gcn_mb1 = (const float*)d_in[14];
    const float* gcn_mW2 = (const float*)d_in[15];
    const float* gcn_mb2 = (const float*)d_in[16];
    const float* gcn_aW1 = (const float*)d_in[17];
    const float* gcn_ab1 = (const float*)d_in[18];
    const float* gcn_aW2 = (const float*)d_in[19];
    const float* gcn_ab2 = (const float*)d_in[20];
    const float* gcn_Wo = (const float*)d_in[21];
    const float* gcn_bo = (const float*)d_in[22];
    const float* gcn_g = (const float*)d_in[23];
    const float* gcn_b = (const float*)d_in[24];
    const float* tmp_emb = (const float*)d_in[25];
    const float* tmp_W1 = (const float*)d_in[26];
    const float* tmp_b1 = (const float*)d_in[27];
    const float* tmp_W2 = (const float*)d_in[28];
    const float* tmp_b2 = (const float*)d_in[29];
    const float* tmp_Wo = (const float*)d_in[30];
    const float* tmp_bo = (const float*)d_in[31];
    const float* tmp_g = (const float*)d_in[32];
    const float* tmp_b = (const float*)d_in[33];
    const float* fus_W = (const float*)d_in[34];
    const float* fus_b = (const float*)d_in[35];
    const float* fus_g = (const float*)d_in[36];
    const float* fus_be = (const float*)d_in[37];

    int N = in_sizes[0] / 128;
    int E = in_sizes[1] / 2;

    // ---- workspace layout (floats) ----
    float* ws = (float*)d_ws;
    float* big = ws;                          // [0,384N): QKV during GAT phase
    float* fused = ws;                        // [0,128N): alias after QKV dead
    float* h_gcn = ws + (size_t)128 * N;      // [128N,256N)
    float* h_tmp = ws + (size_t)256 * N;      // [256N,384N)
    float* scratchB = ws + (size_t)384 * N;   // [384N,512N): Pb slot (obr retired)
    float* agg = ws + (size_t)512 * N;        // [512N,640N): GAT agg / relu-sum s
    float* sm = ws + (size_t)640 * N;         // [640N,648N)
    u32* flags = (u32*)(ws + (size_t)648 * N);
    int* ei32 = (int*)(flags + 16);
    int* nt32 = ei32 + (size_t)2 * E;
    int* tp32 = nt32 + N;
    float* scores = (float*)(tp32 + N);       // E*8 floats
    int* offA = (int*)(scores + (size_t)8 * E);  // N+1
    int* cur = offA + (N + 1);                   // N
    int* srow = cur + N;                         // E
    int* sedge = srow + E;                       // E

    // Pa/Pb aliases (dead slots during each branch's edge phase)
    float* Pa_gcn = ws + (size_t)256 * N;     // h_tmp slot (not yet written)
    float* Pb_gcn = scratchB;
    float* Pa_tmp = ws + (size_t)128 * N;     // h_gcn slot (dead after ep_gcn)
    float* Pb_tmp = scratchB;

    // ---- index canonicalization ----
    k_detect13<<<1, 64, 0, stream>>>((const u32*)d_in[1], (const u32*)d_in[2],
                                     (const u32*)d_in[3], flags);
    long long nEI = (long long)2 * E;
    k_cvt13<<<(int)((nEI + 255) / 256), 256, 0, stream>>>(d_in[1], ei32, nEI, flags, 0);
    k_cvt13<<<(N + 255) / 256, 256, 0, stream>>>(d_in[2], nt32, N, flags, 1);
    k_cvt13<<<(N + 255) / 256, 256, 0, stream>>>(d_in[3], tp32, N, flags, 2);

    int gE = (E + 255) / 256;
    int gN = (N + 255) / 256;
    int gB = (N + 15) / 16;   // 4 waves x 4 nodes per 256-thread block
    int gC = (N + 3) / 4;     // 4 cols (1 wave each) per 256-thread block
    int gE8 = (int)(((long long)E * 8 + 255) / 256);
    int gN128 = (int)(((long long)N * 128 + 255) / 256);

    // ---- counting sort of edges by col (reused by all 3 branches) ----
    kz_i<<<gN, 256, 0, stream>>>(cur, N);
    k_hist<<<gE, 256, 0, stream>>>(ei32, E, cur);
    k_scan<<<1, 1024, 0, stream>>>(cur, offA, N);
    kz_i<<<gN, 256, 0, stream>>>(cur, N);
    k_scatter<<<gE, 256, 0, stream>>>(ei32, E, offA, cur, srow, sedge);

    // ===== GAT branch =====
    kz13<<<(int)(((long long)8 * N + 255) / 256), 256, 0, stream>>>(sm, (long long)8 * N);
    k_qkvB<<<gB, 256, 0, stream>>>(x, gat_Wq, gat_Wk, gat_Wv, big, N);
    k_gat_smB<<<gE8, 256, 0, stream>>>(big, ei32, E, scores, sm);
    k_wvS<<<gC, 256, 0, stream>>>(big, scores, sm, srow, sedge, offA, agg, N);
    k_ep_gatF<<<gB, 256, 0, stream>>>(x, agg, gat_Wo, gat_bo, gat_g, gat_b,
                                      fus_W, fus_b, fused, N);   // QKV dead after this

    // ===== GCN branch =====
    k_hgcnB<<<gB, 256, 0, stream>>>(x, nt32, gcn_Wt, gcn_bt, h_gcn, N);
    k_preB<<<gB, 256, 0, stream>>>(h_gcn, gcn_mW1, gcn_mb1, Pa_gcn, Pb_gcn, N);
    k_rsum<<<gC, 256, 0, stream>>>(Pa_gcn, Pb_gcn, srow, offA, agg, N);
    k_ep_gcnF<<<gB, 256, 0, stream>>>(x, h_gcn, agg, offA, gcn_mW2, gcn_mb2,
                                      gcn_aW1, gcn_ab1, gcn_aW2, gcn_ab2,
                                      gcn_Wo, gcn_bo, gcn_g, gcn_b, fus_W, fused, N);

    // ===== temporal branch =====
    k_htmp13<<<gN128, 256, 0, stream>>>(x, tmp_emb, tp32, h_tmp, N);
    k_preB<<<gB, 256, 0, stream>>>(h_tmp, tmp_W1, tmp_b1, Pa_tmp, Pb_tmp, N);
    k_rsum<<<gC, 256, 0, stream>>>(Pa_tmp, Pb_tmp, srow, offA, agg, N);
    k_ep_tmpF<<<gB, 256, 0, stream>>>(h_tmp, agg, offA, tmp_W2, tmp_b2,
                                      tmp_Wo, tmp_bo, tmp_g, tmp_b, fus_W, fused, N);

    // ===== final (float32 output) =====
    k_finalB<<<gB, 256, 0, stream>>>(fused, fus_g, fus_be, (float*)d_out, N);
}